// Round 1
// baseline (255.731 us; speedup 1.0000x reference)
//
#include <hip/hip_runtime.h>

typedef __attribute__((ext_vector_type(8))) short bf16x8;
typedef __attribute__((ext_vector_type(4))) float f32x4;

#define L2E 1.44269504088896340736f

__device__ __forceinline__ unsigned short f2bf(float x) {
    union { float f; unsigned u; } v; v.f = x;
    return (unsigned short)((v.u + 0x7FFFu + ((v.u >> 16) & 1u)) >> 16);
}
__device__ __forceinline__ float bf2f(unsigned short b) {
    union { unsigned u; float f; } v; v.u = ((unsigned)b) << 16;
    return v.f;
}

#define GLDS(gp, lp) __builtin_amdgcn_global_load_lds( \
    (const __attribute__((address_space(1))) unsigned int*)(const void*)(gp), \
    (__attribute__((address_space(3))) unsigned int*)(void*)(lp), 16, 0, 0)

// ---------------- f32 -> bf16 convert (vectorized) ----------------
__global__ void cvt_bf16(const float* __restrict__ src, unsigned short* __restrict__ dst, int n4) {
    int i = blockIdx.x * blockDim.x + threadIdx.x;
    if (i < n4) {
        float4 v = reinterpret_cast<const float4*>(src)[i];
        ushort4 o;
        o.x = f2bf(v.x); o.y = f2bf(v.y); o.z = f2bf(v.z); o.w = f2bf(v.w);
        reinterpret_cast<ushort4*>(dst)[i] = o;
    }
}

// ---------------- fused QKV projection: C = hs @ W^T + bias ----------------
// A: hs_bf16 [4096][1024], W: [3072][1024] (wq,wk,wv stacked), K=1024
// q_ws/k_ws: [bh][s][d] bf16, v_ws: [bh][d][s] bf16 (transposed for attn staging)
__global__ __launch_bounds__(256, 2) void qkv_proj(
    const unsigned short* __restrict__ A,
    const unsigned short* __restrict__ W,
    const float* __restrict__ bq, const float* __restrict__ bk, const float* __restrict__ bv,
    unsigned short* __restrict__ q_ws, unsigned short* __restrict__ k_ws, unsigned short* __restrict__ v_ws)
{
    __shared__ __align__(16) unsigned short Al[128 * 64];  // [row][64 bf16], 128B rows, swizzled chunks
    __shared__ __align__(16) unsigned short Bl[128 * 64];
    const int mt = blockIdx.x, nt = blockIdx.y;
    const int tid = threadIdx.x, w = tid >> 6, l = tid & 63;
    const int m0 = mt * 128, n0 = nt * 128;
    const int lg = l >> 4, ll = l & 15;
    const int lrow8 = l >> 3, lchunk = l & 7;

    f32x4 acc[4][4] = {};

    for (int kt = 0; kt < 16; ++kt) {
        __syncthreads();
        #pragma unroll
        for (int t = 0; t < 4; ++t) {
            int roff = (w * 4 + t) * 8 + lrow8;          // 0..127
            int sch = lchunk ^ (roff & 7);               // pre-swizzled source chunk
            GLDS(A + (m0 + roff) * 1024 + kt * 64 + sch * 8, Al + (w * 4 + t) * 512);
            GLDS(W + (n0 + roff) * 1024 + kt * 64 + sch * 8, Bl + (w * 4 + t) * 512);
        }
        __syncthreads();
        #pragma unroll
        for (int kk = 0; kk < 2; ++kk) {
            const int cb = kk * 4 + lg;
            bf16x8 af[4], bfr[4];
            #pragma unroll
            for (int fr = 0; fr < 4; ++fr) {
                int row = (w >> 1) * 64 + fr * 16 + ll;
                af[fr] = *reinterpret_cast<const bf16x8*>(Al + row * 64 + ((cb ^ (row & 7)) << 3));
            }
            #pragma unroll
            for (int fc = 0; fc < 4; ++fc) {
                int row = (w & 1) * 64 + fc * 16 + ll;
                bfr[fc] = *reinterpret_cast<const bf16x8*>(Bl + row * 64 + ((cb ^ (row & 7)) << 3));
            }
            #pragma unroll
            for (int fr = 0; fr < 4; ++fr)
                #pragma unroll
                for (int fc = 0; fc < 4; ++fc)
                    acc[fr][fc] = __builtin_amdgcn_mfma_f32_16x16x32_bf16(af[fr], bfr[fc], acc[fr][fc], 0, 0, 0);
        }
    }

    const int matrix = n0 >> 10;  // 0=q 1=k 2=v (tile never straddles: 1024%128==0)
    const float* bias = matrix == 0 ? bq : (matrix == 1 ? bk : bv);
    unsigned short* dst = matrix == 0 ? q_ws : (matrix == 1 ? k_ws : v_ws);
    #pragma unroll
    for (int fc = 0; fc < 4; ++fc) {
        int nloc = (w & 1) * 64 + fc * 16 + ll;
        int o = (n0 + nloc) & 1023;
        float bb = bias[o];
        int h = o >> 6, dd = o & 63;
        #pragma unroll
        for (int fr = 0; fr < 4; ++fr) {
            int rbase = (w >> 1) * 64 + fr * 16 + (lg << 2);
            #pragma unroll
            for (int e = 0; e < 4; ++e) {
                int mg = m0 + rbase + e;
                int b = mg >> 10, s = mg & 1023;
                int bh = b * 16 + h;
                unsigned short val = f2bf(acc[fr][fc][e] + bb);
                if (matrix < 2) dst[(bh * 1024 + s) * 64 + dd] = val;
                else            dst[(bh * 64 + dd) * 1024 + s] = val;
            }
        }
    }
}

// ---------------- fused attention with relative_key_query bias ----------------
// grid: (16 q-tiles, 64 bh), block 256 (4 waves). Each wave owns 16 q-rows.
// Per 64-col k-tile: S=QK^T (MFMA), QD=Q@Dw^T, KD=K@Dw^T (MFMA, 127-row dist window),
// diagonal gather of bias, online softmax, PV (MFMA, V^T staged).
__global__ __launch_bounds__(256, 2) void git_attn(
    const unsigned short* __restrict__ q_ws,
    const unsigned short* __restrict__ k_ws,
    const unsigned short* __restrict__ v_ws,
    const unsigned short* __restrict__ Dbf,   // [2048][64] bf16 (rows 0..2046 valid)
    float* __restrict__ out)
{
    __shared__ __align__(16) char smem[75776];
    unsigned short* K_l  = (unsigned short*)(smem);           // [64][64]  8KB swz
    unsigned short* Vt_l = (unsigned short*)(smem + 8192);    // [64 d][64 j] 8KB swz
    unsigned short* Dw_l = (unsigned short*)(smem + 16384);   // [128][64] 16KB swz
    unsigned short* QDt  = (unsigned short*)(smem + 32768);   // [128 t][68 i] 17408B
    unsigned short* KDt  = (unsigned short*)(smem + 50176);   // [128 t][68 j] 17408B
    unsigned short* P_l  = (unsigned short*)(smem + 67584);   // [4 waves][16][64] 8KB swz

    const int qt = blockIdx.x, bh = blockIdx.y;
    const int l0 = qt * 64;
    const int tid = threadIdx.x, w = tid >> 6, l = tid & 63;
    const int lg = l >> 4, ll = l & 15;
    const int lrow8 = l >> 3, lchunk = l & 7;

    const unsigned short* qb = q_ws + bh * 65536;
    const unsigned short* kb = k_ws + bh * 65536;
    const unsigned short* vb = v_ws + bh * 65536;

    // Q fragments (rows l0+16w+ll), hoisted for whole kernel
    bf16x8 qf[2];
    {
        int row = l0 + 16 * w + ll;
        qf[0] = *reinterpret_cast<const bf16x8*>(qb + row * 64 + lg * 8);
        qf[1] = *reinterpret_cast<const bf16x8*>(qb + row * 64 + lg * 8 + 32);
    }

    f32x4 Oacc[4] = {};
    float mrow[4] = {-1e30f, -1e30f, -1e30f, -1e30f};
    float lrow[4] = {};
    unsigned short* Pw = P_l + w * 1024;

    for (int rt = 0; rt < 16; ++rt) {
        const int r0 = rt * 64;
        const int m0 = l0 - r0 + 960;     // dist window base row
        __syncthreads();
        // ---- stage K tile, V^T tile, Dw window (global_load_lds, pre-swizzled src) ----
        #pragma unroll
        for (int t = 0; t < 2; ++t) {
            int row = (w * 2 + t) * 8 + lrow8;        // 0..63
            int sch = lchunk ^ (row & 7);
            GLDS(kb + (r0 + row) * 64 + sch * 8, K_l + (w * 2 + t) * 512);
            GLDS(vb + row * 1024 + r0 + sch * 8, Vt_l + (w * 2 + t) * 512);
        }
        #pragma unroll
        for (int t = 0; t < 4; ++t) {
            int row = (w * 4 + t) * 8 + lrow8;        // 0..127
            int srow = m0 + row; srow = srow > 2046 ? 2046 : srow;  // row 127 unused
            int sch = lchunk ^ (row & 7);
            GLDS(Dbf + srow * 64 + sch * 8, Dw_l + (w * 4 + t) * 512);
        }
        __syncthreads();

        // ---- S = Q K^T ----
        f32x4 Sacc[4] = {};
        bf16x8 kaf[2];
        #pragma unroll
        for (int kk = 0; kk < 2; ++kk) {
            const int cb = kk * 4 + lg;
            #pragma unroll
            for (int jt = 0; jt < 4; ++jt) {
                int row = jt * 16 + ll;
                bf16x8 kf = *reinterpret_cast<const bf16x8*>(K_l + row * 64 + ((cb ^ (row & 7)) << 3));
                Sacc[jt] = __builtin_amdgcn_mfma_f32_16x16x32_bf16(qf[kk], kf, Sacc[jt], 0, 0, 0);
            }
            int row = 16 * w + ll;  // this wave's K rows (A-operand for KD)
            kaf[kk] = *reinterpret_cast<const bf16x8*>(K_l + row * 64 + ((cb ^ (row & 7)) << 3));
        }
        // ---- QD = Q@Dw^T, KD = K@Dw^T (shared Dw B-fragments) ----
        f32x4 QDacc[8] = {}; f32x4 KDacc[8] = {};
        #pragma unroll
        for (int kk = 0; kk < 2; ++kk) {
            const int cb = kk * 4 + lg;
            #pragma unroll
            for (int tt = 0; tt < 8; ++tt) {
                int row = tt * 16 + ll;
                bf16x8 df = *reinterpret_cast<const bf16x8*>(Dw_l + row * 64 + ((cb ^ (row & 7)) << 3));
                QDacc[tt] = __builtin_amdgcn_mfma_f32_16x16x32_bf16(qf[kk],  df, QDacc[tt], 0, 0, 0);
                KDacc[tt] = __builtin_amdgcn_mfma_f32_16x16x32_bf16(kaf[kk], df, KDacc[tt], 0, 0, 0);
            }
        }
        // ---- write QDt/KDt transposed [t][i] (packed 4 bf16 = 8B, 136B rows) ----
        {
            int i0 = 16 * w + (lg << 2);
            #pragma unroll
            for (int tt = 0; tt < 8; ++tt) {
                int t = ll + 16 * tt;
                ushort4 qa, ka;
                qa.x = f2bf(QDacc[tt][0]); qa.y = f2bf(QDacc[tt][1]); qa.z = f2bf(QDacc[tt][2]); qa.w = f2bf(QDacc[tt][3]);
                ka.x = f2bf(KDacc[tt][0]); ka.y = f2bf(KDacc[tt][1]); ka.z = f2bf(KDacc[tt][2]); ka.w = f2bf(KDacc[tt][3]);
                *reinterpret_cast<ushort4*>(QDt + t * 68 + i0) = qa;
                *reinterpret_cast<ushort4*>(KDt + t * 68 + i0) = ka;
            }
        }
        __syncthreads();   // KD complete (written cooperatively, read by all waves)

        // ---- gather bias, scale, online softmax ----
        float pvv[4][4];
        float rm[4] = {-1e30f, -1e30f, -1e30f, -1e30f};
        #pragma unroll
        for (int jt = 0; jt < 4; ++jt) {
            int j = ll + 16 * jt;
            #pragma unroll
            for (int e = 0; e < 4; ++e) {
                int i = 16 * w + (lg << 2) + e;
                int t = i - j + 63;                       // 0..126
                float sv = (Sacc[jt][e] + bf2f(QDt[t * 68 + i]) + bf2f(KDt[t * 68 + j])) * 0.125f;
                pvv[jt][e] = sv;
                rm[e] = fmaxf(rm[e], sv);
            }
        }
        #pragma unroll
        for (int e = 0; e < 4; ++e) {
            #pragma unroll
            for (int msk = 1; msk < 16; msk <<= 1)
                rm[e] = fmaxf(rm[e], __shfl_xor(rm[e], msk, 64));
        }
        float psum[4];
        #pragma unroll
        for (int e = 0; e < 4; ++e) {
            float mn = fmaxf(mrow[e], rm[e]);
            float sc = exp2f((mrow[e] - mn) * L2E);
            mrow[e] = mn;
            lrow[e] *= sc;
            #pragma unroll
            for (int dt = 0; dt < 4; ++dt) Oacc[dt][e] *= sc;
            float ps = 0.f;
            #pragma unroll
            for (int jt = 0; jt < 4; ++jt) {
                float p = exp2f((pvv[jt][e] - mn) * L2E);
                pvv[jt][e] = p;
                ps += p;
            }
            psum[e] = ps;
        }
        #pragma unroll
        for (int e = 0; e < 4; ++e) {
            #pragma unroll
            for (int msk = 1; msk < 16; msk <<= 1)
                psum[e] += __shfl_xor(psum[e], msk, 64);
            lrow[e] += psum[e];
        }
        // ---- write P (bf16, per-wave private, swizzled rows) ----
        #pragma unroll
        for (int jt = 0; jt < 4; ++jt) {
            int j = ll + 16 * jt;
            #pragma unroll
            for (int e = 0; e < 4; ++e) {
                int i16 = (lg << 2) + e;
                Pw[i16 * 64 + (((j >> 3) ^ (i16 & 7)) << 3) + (j & 7)] = f2bf(pvv[jt][e]);
            }
        }
        // ---- O += P V  (V^T in LDS; same-wave P write->read, DS pipe in order) ----
        #pragma unroll
        for (int jj = 0; jj < 2; ++jj) {
            const int cb = jj * 4 + lg;
            bf16x8 pf = *reinterpret_cast<const bf16x8*>(Pw + ll * 64 + ((cb ^ (ll & 7)) << 3));
            #pragma unroll
            for (int dt = 0; dt < 4; ++dt) {
                int row = dt * 16 + ll;                   // Vt row = d
                bf16x8 vf = *reinterpret_cast<const bf16x8*>(Vt_l + row * 64 + ((cb ^ (row & 7)) << 3));
                Oacc[dt] = __builtin_amdgcn_mfma_f32_16x16x32_bf16(pf, vf, Oacc[dt], 0, 0, 0);
            }
        }
    }

    // ---- epilogue: out[b][s][h*64+d] = O / l ----
    const int b = bh >> 4, h = bh & 15;
    #pragma unroll
    for (int e = 0; e < 4; ++e) {
        float inv = 1.f / lrow[e];
        int s = l0 + 16 * w + (lg << 2) + e;
        #pragma unroll
        for (int dt = 0; dt < 4; ++dt) {
            int d = ll + 16 * dt;
            out[((b * 1024 + s) * 16 + h) * 64 + d] = Oacc[dt][e] * inv;
        }
    }
}

// ---------------- launch ----------------
extern "C" void kernel_launch(void* const* d_in, const int* in_sizes, int n_in,
                              void* d_out, int out_size, void* d_ws, size_t ws_size,
                              hipStream_t stream) {
    const float* hs = (const float*)d_in[0];
    const float* wq = (const float*)d_in[1];
    const float* bq = (const float*)d_in[2];
    const float* wk = (const float*)d_in[3];
    const float* bk = (const float*)d_in[4];
    const float* wv = (const float*)d_in[5];
    const float* bv = (const float*)d_in[6];
    const float* de = (const float*)d_in[7];
    float* out = (float*)d_out;
    char* ws = (char*)d_ws;

    unsigned short* hs_bf = (unsigned short*)(ws);              // 8 MB  [4096][1024]
    unsigned short* w_bf  = (unsigned short*)(ws + 8388608);    // 6 MB  [3072][1024]
    unsigned short* D_bf  = (unsigned short*)(ws + 14680064);   // 256KB [2048][64]
    unsigned short* q_ws  = (unsigned short*)(ws + 14942208);   // 8 MB  [64][1024][64]
    unsigned short* k_ws  = (unsigned short*)(ws + 23330816);   // 8 MB
    unsigned short* v_ws  = (unsigned short*)(ws + 31719424);   // 8 MB  [64][64][1024]
    // total 40,108,032 bytes of d_ws

    int n4;
    n4 = 4096 * 1024 / 4;
    cvt_bf16<<<(n4 + 255) / 256, 256, 0, stream>>>(hs, hs_bf, n4);
    n4 = 1024 * 1024 / 4;
    cvt_bf16<<<(n4 + 255) / 256, 256, 0, stream>>>(wq, w_bf,           n4);
    cvt_bf16<<<(n4 + 255) / 256, 256, 0, stream>>>(wk, w_bf + 1048576, n4);
    cvt_bf16<<<(n4 + 255) / 256, 256, 0, stream>>>(wv, w_bf + 2097152, n4);
    n4 = 2047 * 64 / 4;
    cvt_bf16<<<(n4 + 255) / 256, 256, 0, stream>>>(de, D_bf, n4);

    qkv_proj<<<dim3(32, 24), 256, 0, stream>>>(hs_bf, w_bf, bq, bk, bv, q_ws, k_ws, v_ws);
    git_attn<<<dim3(16, 64), 256, 0, stream>>>(q_ws, k_ws, v_ws, D_bf, out);
}